// Round 13
// baseline (253.940 us; speedup 1.0000x reference)
//
#include <hip/hip_runtime.h>

#define BB 8
#define CC 192
#define C2 384
#define HH 128
#define WW 128
#define NN 16384
#define NHEADS 4
#define HC 48
#define LTK 196   // LDS row stride in u16 (392 B)
#define LTK2 98   // same in u32
// qkv_blk layout:  [b][p=img row][384 ch][128]  (each k1 block writes 96 KiB stream)
// vdw_blk layout:  [b][p][192 ch][128]

typedef float f32x2 __attribute__((ext_vector_type(2)));
typedef float f32x4 __attribute__((ext_vector_type(4)));
typedef float f32x16 __attribute__((ext_vector_type(16)));
typedef short s16x4 __attribute__((ext_vector_type(4)));
typedef short s16x8 __attribute__((ext_vector_type(8)));
typedef unsigned short u16;
typedef u16 u16x4 __attribute__((ext_vector_type(4)));
typedef u16 u16x8 __attribute__((ext_vector_type(8)));
typedef unsigned int u32;

__device__ __forceinline__ float bfu2f(u32 u16v) {
  return __uint_as_float(u16v << 16);
}
__device__ __forceinline__ u16 f2bfu(float f) {
  u32 u = __float_as_uint(f);
  return (u16)((u + 0x7fffu + ((u >> 16) & 1u)) >> 16);
}
__device__ __forceinline__ s16x8 ldpair(const u16* p) {
  s16x4 lo = *reinterpret_cast<const s16x4*>(p);
  s16x4 hi = *reinterpret_cast<const s16x4*>(p + 16);
  return __builtin_shufflevector(lo, hi, 0, 1, 2, 3, 4, 5, 6, 7);
}
__device__ __forceinline__ s16x8 ldb64pair(const u32* p) {
  s16x4 lo = *reinterpret_cast<const s16x4*>(p);
  s16x4 hi = *reinterpret_cast<const s16x4*>(p + 2);
  return __builtin_shufflevector(lo, hi, 0, 1, 2, 3, 4, 5, 6, 7);
}

// ---------------------------------------------------------------------------
// K0a: w_qkv fp32 -> bf16
// ---------------------------------------------------------------------------
__global__ __launch_bounds__(256) void k0_wcvt(const float* __restrict__ w,
                                               u16* __restrict__ wbf) {
  const int i = (blockIdx.x * 256 + threadIdx.x) * 4;
  f32x4 v = *reinterpret_cast<const f32x4*>(&w[i]);
  u16x4 o;
  o[0] = f2bfu(v[0]); o[1] = f2bfu(v[1]); o[2] = f2bfu(v[2]); o[3] = f2bfu(v[3]);
  *reinterpret_cast<u16x4*>(&wbf[i]) = o;
}

// ---------------------------------------------------------------------------
// K1 (r9 structure, blocked output): stage x-panel once, 3 o-tiles, E/O col
// frags, packed u32 stores into qkv_blk (contiguous 96 KiB per block).
// grid (128, 8), 512 thr.
// ---------------------------------------------------------------------------
__global__ __launch_bounds__(512, 4) void k1_qkv(
    const float* __restrict__ x, const u16* __restrict__ wbf,
    u16* __restrict__ qblk) {
  const int bx = blockIdx.x;
  const int p0 = ((bx & 7) << 4) + (bx >> 3);          // panel, bijective 128
  const int n0 = p0 << 7;
  const int b  = blockIdx.y;
  __shared__ u16 Xs[128 * LTK];
  u32* Xsw = reinterpret_cast<u32*>(Xs);
  const int t = threadIdx.x, lane = t & 63;
  const int wid = t >> 6, wo = wid >> 1, wn = wid & 1;
  const int l31 = lane & 31, g2 = lane >> 5;

  {
    const int nq = t & 31, cr = t >> 5;
    const int kpb = cr >> 1;
    const int jh = cr & 1;
    const int prA = 2 * nq + jh;
    const int prB = 64 + 2 * nq + jh;
    const float* xb = x + (size_t)b * CC * NN + n0 + 4 * nq;
    #pragma unroll 6
    for (int i = 0; i < 12; ++i) {
      f32x4 v = *reinterpret_cast<const f32x4*>(xb + (size_t)(cr + 16 * i) * NN);
      u32 A  = (u32)f2bfu(v[0]) | ((u32)f2bfu(v[1]) << 16);
      u32 Bp = (u32)f2bfu(v[2]) | ((u32)f2bfu(v[3]) << 16);
      u32 oA = __shfl_xor(A, 32);
      u32 oB = __shfl_xor(Bp, 32);
      u32 va, vb;
      if (jh) {
        va = (oB & 0xffffu) | (Bp << 16);
        vb = (oB >> 16) | (Bp & 0xffff0000u);
      } else {
        va = (A & 0xffffu) | (oA << 16);
        vb = (A >> 16) | (oA & 0xffff0000u);
      }
      const int col = kpb + 8 * i;
      Xsw[prA * LTK2 + col] = va;
      Xsw[prB * LTK2 + col] = vb;
    }
  }
  __syncthreads();

  const int nb2 = wn * 32;
  const u32* browE = &Xsw[(nb2 + l31) * LTK2 + 4 * g2];
  const u32* browO = &Xsw[(64 + nb2 + l31) * LTK2 + 4 * g2];
  u16* dstbase = qblk + ((size_t)(b * 128 + p0) * C2) * 128;

  for (int ot = 0; ot < 3; ++ot) {
    const int o0 = ot * 128;
    const u16* wr = wbf + (size_t)(o0 + wo * 32 + l31) * CC + 8 * g2;

    s16x8 afA[6], afB[6];
    #pragma unroll
    for (int s = 0; s < 6; ++s) {
      afA[s] = *reinterpret_cast<const s16x8*>(wr + s * 32);
      afB[s] = *reinterpret_cast<const s16x8*>(wr + s * 32 + 16);
    }

    f32x16 accE, accO;
    #pragma unroll
    for (int e = 0; e < 16; ++e) { accE[e] = 0.f; accO[e] = 0.f; }

    #pragma unroll
    for (int s = 0; s < 6; ++s) {
      s16x8 bfE0 = ldb64pair(browE + 16 * s);
      s16x8 bfE1 = ldb64pair(browE + 16 * s + 8);
      s16x8 bfO0 = ldb64pair(browO + 16 * s);
      s16x8 bfO1 = ldb64pair(browO + 16 * s + 8);
      accE = __builtin_amdgcn_mfma_f32_32x32x16_bf16(afA[s], bfE0, accE, 0, 0, 0);
      accO = __builtin_amdgcn_mfma_f32_32x32x16_bf16(afA[s], bfO0, accO, 0, 0, 0);
      accE = __builtin_amdgcn_mfma_f32_32x32x16_bf16(afB[s], bfE1, accE, 0, 0, 0);
      accO = __builtin_amdgcn_mfma_f32_32x32x16_bf16(afB[s], bfO1, accO, 0, 0, 0);
    }
    #pragma unroll
    for (int r = 0; r < 16; ++r) {
      const int row = (r & 3) + 8 * (r >> 2) + 4 * g2;
      const u32 pk = (u32)f2bfu(accE[r]) | ((u32)f2bfu(accO[r]) << 16);
      *reinterpret_cast<u32*>(
          &dstbase[(o0 + wo * 32 + row) * 128 + wn * 64 + 2 * l31]) = pk;
    }
  }
}

// ---------------------------------------------------------------------------
// K2: 3x3 depthwise on the V half, blocked in/out. Block = (y, b): all 192
// v-channels of one image row; reads 3 contiguous panels. grid (128, 8), 256t.
// ---------------------------------------------------------------------------
__global__ __launch_bounds__(256) void k2_dw(
    const u16* __restrict__ qblk, const float* __restrict__ wdw,
    u16* __restrict__ vblk) {
  const int y = blockIdx.x;
  const int b = blockIdx.y;
  const int t = threadIdx.x;
  #pragma unroll
  for (int it = 0; it < 12; ++it) {
    const int idx = t + 256 * it;          // 0..3071
    const int ch = idx >> 4;               // 0..191
    const int grp = idx & 15;
    const int x0 = grp * 8;
    const float* wv = wdw + (CC + ch) * 9;
    float o[8];
    #pragma unroll
    for (int j = 0; j < 8; ++j) o[j] = 0.f;
    #pragma unroll
    for (int dy = 0; dy < 3; ++dy) {
      const int gy = y + dy - 1;
      if ((unsigned)gy < (unsigned)HH) {
        const u16* rp = qblk + ((size_t)(b * 128 + gy) * C2 + CC + ch) * 128;
        u16x8 m = *reinterpret_cast<const u16x8*>(&rp[x0]);
        float px[10];
        px[0] = (x0 > 0) ? bfu2f(rp[x0 - 1]) : 0.f;
        px[9] = (x0 < 120) ? bfu2f(rp[x0 + 8]) : 0.f;
        #pragma unroll
        for (int j = 0; j < 8; ++j) px[j + 1] = bfu2f(m[j]);
        const float w0 = wv[dy * 3 + 0], w1 = wv[dy * 3 + 1], w2 = wv[dy * 3 + 2];
        #pragma unroll
        for (int j = 0; j < 8; ++j)
          o[j] += w0 * px[j] + w1 * px[j + 1] + w2 * px[j + 2];
      }
    }
    u16x8 ov;
    #pragma unroll
    for (int j = 0; j < 8; ++j) ov[j] = f2bfu(o[j]);
    *reinterpret_cast<u16x8*>(
        &vblk[((size_t)(b * 128 + y) * 192 + ch) * 128 + x0]) = ov;
  }
}

// ---------------------------------------------------------------------------
// K23: fused depthwise-conv (q) + partial Gram, blocked input.
// Block = (rp, h, b): output rows 2rp,2rp+1; stage 4 panels' q-channels
// (contiguous 12 KiB each) -> conv -> symmetric Gram MFMA -> reduce.
// grid (64, 4, 8), 256 thr.
// ---------------------------------------------------------------------------
__global__ __launch_bounds__(256, 2) void k23_convgram(
    const u16* __restrict__ qblk, const float* __restrict__ wdw,
    float* __restrict__ gpart) {
  const int raw = blockIdx.x;
  const int rp = ((raw & 7) << 3) + (raw >> 3);   // bijective 64
  const int h = blockIdx.y, b = blockIdx.z;
  __shared__ u16 inq[48 * 520];    // 4 input rows x 128, stride 520 u16
  __shared__ float wsm[432];
  __shared__ u16 qd[48 * 264];     // conv out 48 x 256, stride 264
  const int t = threadIdx.x, lane = t & 63, wv = t >> 6;
  const int l15 = lane & 15, g = lane >> 4;

  for (int idx = t; idx < 432; idx += 256) wsm[idx] = wdw[h * 432 + idx];
  #pragma unroll
  for (int it = 0; it < 12; ++it) {
    const int idx = t + 256 * it;          // 0..3071
    const int ch = idx >> 6, rem = idx & 63;
    const int iy = rem >> 4, grp = rem & 15;
    const int gy = 2 * rp - 1 + iy;
    u16x8 v;
    #pragma unroll
    for (int e = 0; e < 8; ++e) v[e] = 0;
    if ((unsigned)gy < (unsigned)HH)
      v = *reinterpret_cast<const u16x8*>(
          qblk + ((size_t)(b * 128 + gy) * C2 + h * HC + ch) * 128 + grp * 8);
    *reinterpret_cast<u16x8*>(&inq[ch * 520 + iy * 128 + grp * 8]) = v;
  }
  __syncthreads();

  #pragma unroll
  for (int it = 0; it < 6; ++it) {
    const int idx = t + 256 * it;
    const int ch = idx >> 5, grp = idx & 31;
    const int p0 = grp * 8;
    const int orow = p0 >> 7, x0 = p0 & 127;
    float o[8];
    #pragma unroll
    for (int j = 0; j < 8; ++j) o[j] = 0.f;
    #pragma unroll
    for (int dy = 0; dy < 3; ++dy) {
      const u16* rp_ = &inq[ch * 520 + (orow + dy) * 128];
      u16x8 m = *reinterpret_cast<const u16x8*>(&rp_[x0]);
      float px[10];
      px[0] = (x0 > 0) ? bfu2f(rp_[x0 - 1]) : 0.f;
      px[9] = (x0 < 120) ? bfu2f(rp_[x0 + 8]) : 0.f;
      #pragma unroll
      for (int j = 0; j < 8; ++j) px[j + 1] = bfu2f(m[j]);
      const float w0 = wsm[ch * 9 + dy * 3 + 0];
      const float w1 = wsm[ch * 9 + dy * 3 + 1];
      const float w2 = wsm[ch * 9 + dy * 3 + 2];
      #pragma unroll
      for (int j = 0; j < 8; ++j)
        o[j] += w0 * px[j] + w1 * px[j + 1] + w2 * px[j + 2];
    }
    u16x8 ov;
    #pragma unroll
    for (int j = 0; j < 8; ++j) ov[j] = f2bfu(o[j]);
    *reinterpret_cast<u16x8*>(&qd[ch * 264 + p0]) = ov;
  }
  __syncthreads();

  f32x4 acc[3][3];
  #pragma unroll
  for (int i = 0; i < 3; ++i)
    #pragma unroll
    for (int j = 0; j < 3; ++j)
      #pragma unroll
      for (int e = 0; e < 4; ++e) acc[i][j][e] = 0.f;

  #pragma unroll
  for (int s = 0; s < 2; ++s) {
    const int n = wv * 64 + s * 32;
    s16x8 cf[3];
    #pragma unroll
    for (int i = 0; i < 3; ++i)
      cf[i] = ldpair(&qd[(i * 16 + l15) * 264 + n + 4 * g]);
    #pragma unroll
    for (int i = 0; i < 3; ++i)
      #pragma unroll
      for (int j = 0; j < 3; ++j)
        acc[i][j] = __builtin_amdgcn_mfma_f32_16x16x32_bf16(cf[i], cf[j], acc[i][j], 0, 0, 0);
  }

  float* red = reinterpret_cast<float*>(inq);
  #pragma unroll
  for (int i = 0; i < 3; ++i)
    #pragma unroll
    for (int j = 0; j < 3; ++j)
      #pragma unroll
      for (int r = 0; r < 4; ++r)
        red[wv * 2304 + (i * 16 + 4 * g + r) * 48 + j * 16 + l15] = acc[i][j][r];
  __syncthreads();
  float* gp = gpart + (size_t)b * 589824 + h * 147456 + rp * 2304;
  for (int idx = t; idx < 2304; idx += 256)
    gp[idx] = red[idx] + red[2304 + idx] + red[4608 + idx] + red[6912 + idx];
}

// ---------------------------------------------------------------------------
// K4: reduce 64 partials + normalize + softmax. grid 32, 256 thr.
// ---------------------------------------------------------------------------
__global__ __launch_bounds__(256) void k4_soft(
    const float* __restrict__ gpart, const float* __restrict__ temp,
    float* __restrict__ attn) {
  const int bh = blockIdx.x;
  const int b = bh >> 2, h = bh & 3;
  const int t = threadIdx.x;
  __shared__ float G[2304];
  __shared__ float rn[48];
  const float* gp = gpart + (size_t)b * 589824 + h * 147456;
  for (int idx = t; idx < 2304; idx += 256) {
    float s = 0.f;
    #pragma unroll 8
    for (int c = 0; c < 64; ++c) s += gp[c * 2304 + idx];
    G[idx] = s;
  }
  __syncthreads();
  if (t < 48) rn[t] = rsqrtf(G[t * 48 + t]);
  __syncthreads();
  if (t < 48) {
    const float tm = temp[h];
    float v[48];
    float mx = -1e30f;
    #pragma unroll
    for (int j = 0; j < 48; ++j) {
      v[j] = G[t * 48 + j] * rn[t] * rn[j] * tm;
      mx = fmaxf(mx, v[j]);
    }
    float s = 0.f;
    #pragma unroll
    for (int j = 0; j < 48; ++j) { v[j] = expf(v[j] - mx); s += v[j]; }
    const float inv = 1.f / s;
    #pragma unroll
    for (int j = 0; j < 48; ++j)
      attn[(size_t)bh * 2304 + t * 48 + j] = v[j] * inv;
  }
}

// ---------------------------------------------------------------------------
// K5: M = w_proj x blockdiag(attn) -> bf16 (unchanged)
// ---------------------------------------------------------------------------
__global__ __launch_bounds__(192) void k5_M(
    const float* __restrict__ wproj, const float* __restrict__ attn,
    u16* __restrict__ Mbf) {
  const int o = blockIdx.x;
  const int b = blockIdx.y;
  const int d = threadIdx.x;
  const int h = d / HC, dl = d % HC;
  const float* wrow = wproj + o * CC + h * HC;
  const float* at = attn + ((size_t)(b * NHEADS + h)) * 2304;
  float s = 0.f;
  #pragma unroll
  for (int c = 0; c < HC; ++c) s = fmaf(wrow[c], at[c * HC + dl], s);
  Mbf[((size_t)b * CC + o) * CC + d] = f2bfu(s);
}

// ---------------------------------------------------------------------------
// K6: out = M x v_dw. v staged from blocked vblk (contiguous 48 KiB panel).
// Nontemporal f32x2 out stores. grid (128, 8), 256 thr.
// ---------------------------------------------------------------------------
__global__ __launch_bounds__(256, 4) void k6_out(
    const u16* __restrict__ Mbf, const u16* __restrict__ vblk,
    float* __restrict__ out) {
  const int bx = blockIdx.x;
  const int p0 = ((bx & 7) << 4) + (bx >> 3);
  const int n0 = p0 << 7;
  const int b  = blockIdx.y;
  __shared__ u16 Vs[128 * LTK];
  u32* Vsw = reinterpret_cast<u32*>(Vs);
  const int t = threadIdx.x, lane = t & 63;
  const int wid = t >> 6, wo = wid >> 1, wn = wid & 1;
  const int l31 = lane & 31, g2 = lane >> 5;

  {
    const int nq = t & 31, cr = t >> 5;
    const int kpb = cr >> 1;
    const int jh = cr & 1;
    const int prA = 2 * nq + jh;
    const int prB = 64 + 2 * nq + jh;
    const u16* vbp = vblk + (size_t)(b * 128 + p0) * 192 * 128 + 4 * nq;
    #pragma unroll 6
    for (int i = 0; i < 24; ++i) {
      u16x4 m = *reinterpret_cast<const u16x4*>(vbp + (cr + 8 * i) * 128);
      u32 A  = (u32)m[0] | ((u32)m[1] << 16);
      u32 Bp = (u32)m[2] | ((u32)m[3] << 16);
      u32 oA = __shfl_xor(A, 32);
      u32 oB = __shfl_xor(Bp, 32);
      u32 va, vb;
      if (jh) {
        va = (oB & 0xffffu) | (Bp << 16);
        vb = (oB >> 16) | (Bp & 0xffff0000u);
      } else {
        va = (A & 0xffffu) | (oA << 16);
        vb = (A >> 16) | (oA & 0xffff0000u);
      }
      const int col = kpb + 4 * i;
      Vsw[prA * LTK2 + col] = va;
      Vsw[prB * LTK2 + col] = vb;
    }
  }
  __syncthreads();

  const int nb2 = wn * 32;
  const u32* browE = &Vsw[(nb2 + l31) * LTK2 + 4 * g2];
  const u32* browO = &Vsw[(64 + nb2 + l31) * LTK2 + 4 * g2];
  const u16* Ab = Mbf + (size_t)b * CC * CC;

  for (int ot = 0; ot < 3; ++ot) {
    const int o0 = ot * 64;
    const u16* ar = Ab + (size_t)(o0 + wo * 32 + l31) * CC + 8 * g2;

    s16x8 afA[6], afB[6];
    #pragma unroll
    for (int s = 0; s < 6; ++s) {
      afA[s] = *reinterpret_cast<const s16x8*>(ar + s * 32);
      afB[s] = *reinterpret_cast<const s16x8*>(ar + s * 32 + 16);
    }

    f32x16 accE, accO;
    #pragma unroll
    for (int e = 0; e < 16; ++e) { accE[e] = 0.f; accO[e] = 0.f; }

    #pragma unroll
    for (int s = 0; s < 6; ++s) {
      s16x8 bfE0 = ldb64pair(browE + 16 * s);
      s16x8 bfE1 = ldb64pair(browE + 16 * s + 8);
      s16x8 bfO0 = ldb64pair(browO + 16 * s);
      s16x8 bfO1 = ldb64pair(browO + 16 * s + 8);
      accE = __builtin_amdgcn_mfma_f32_32x32x16_bf16(afA[s], bfE0, accE, 0, 0, 0);
      accO = __builtin_amdgcn_mfma_f32_32x32x16_bf16(afA[s], bfO0, accO, 0, 0, 0);
      accE = __builtin_amdgcn_mfma_f32_32x32x16_bf16(afB[s], bfE1, accE, 0, 0, 0);
      accO = __builtin_amdgcn_mfma_f32_32x32x16_bf16(afB[s], bfO1, accO, 0, 0, 0);
    }
    #pragma unroll
    for (int r = 0; r < 16; ++r) {
      const int row = (r & 3) + 8 * (r >> 2) + 4 * g2;
      f32x2 st;
      st[0] = accE[r];
      st[1] = accO[r];
      f32x2* op = reinterpret_cast<f32x2*>(
          &out[((size_t)b * CC + o0 + wo * 32 + row) * NN + n0 + wn * 64 + 2 * l31]);
      __builtin_nontemporal_store(st, op);
    }
  }
}

// ---------------------------------------------------------------------------
extern "C" void kernel_launch(void* const* d_in, const int* in_sizes, int n_in,
                              void* d_out, int out_size, void* d_ws, size_t ws_size,
                              hipStream_t stream) {
  const float* x      = (const float*)d_in[0];
  const float* w_qkv  = (const float*)d_in[1];
  const float* w_dw   = (const float*)d_in[2];
  const float* w_proj = (const float*)d_in[3];
  const float* temp   = (const float*)d_in[4];
  float* out = (float*)d_out;

  const size_t OFF_QKV   = 0;               // bf16 blk  8*128*384*128 = 100,663,296
  const size_t OFF_VDW   = 100663296ULL;    // bf16 blk  8*128*192*128 =  50,331,648
  const size_t OFF_GPART = 150994944ULL;    // f32  8*4*64*2304        =  18,874,368
  const size_t OFF_ATTN  = 206045184ULL;    // f32  32*2304
  const size_t OFF_M     = 206340096ULL;    // bf16 8*192*192
  const size_t OFF_WBF   = 206929920ULL;    // bf16 384*192
  const size_t NEEDED    = 207077376ULL;
  if (ws_size < NEEDED) return;

  char* ws = (char*)d_ws;
  u16* qblk  = (u16*)(ws + OFF_QKV);
  u16* vblk  = (u16*)(ws + OFF_VDW);
  float* gpart = (float*)(ws + OFF_GPART);
  float* attn  = (float*)(ws + OFF_ATTN);
  u16* Mbf   = (u16*)(ws + OFF_M);
  u16* wbf   = (u16*)(ws + OFF_WBF);

  k0_wcvt<<<dim3(72), 256, 0, stream>>>(w_qkv, wbf);
  k1_qkv <<<dim3(128, 8), 512, 0, stream>>>(x, wbf, qblk);
  k2_dw  <<<dim3(128, 8), 256, 0, stream>>>(qblk, w_dw, vblk);
  k23_convgram<<<dim3(64, NHEADS, BB), 256, 0, stream>>>(qblk, w_dw, gpart);
  k4_soft<<<dim3(BB * NHEADS), 256, 0, stream>>>(gpart, temp, attn);
  k5_M   <<<dim3(CC, BB), 192, 0, stream>>>(w_proj, attn, Mbf);
  k6_out <<<dim3(128, 8), 256, 0, stream>>>(Mbf, vblk, out);
}

// Round 14
// 226.396 us; speedup vs baseline: 1.1217x; 1.1217x over previous
//
#include <hip/hip_runtime.h>

#define BB 8
#define CC 192
#define C2 384
#define HH 128
#define WW 128
#define NN 16384
#define NHEADS 4
#define HC 48
#define LTK 196   // LDS row stride in u16 (392 B)
#define LTK2 98   // same in u32
// LDS physical row map: phys(n) = (n>>1) + 64*(n&1)

typedef float f32x2 __attribute__((ext_vector_type(2)));
typedef float f32x4 __attribute__((ext_vector_type(4)));
typedef float f32x16 __attribute__((ext_vector_type(16)));
typedef short s16x4 __attribute__((ext_vector_type(4)));
typedef short s16x8 __attribute__((ext_vector_type(8)));
typedef unsigned short u16;
typedef u16 u16x4 __attribute__((ext_vector_type(4)));
typedef u16 u16x8 __attribute__((ext_vector_type(8)));
typedef unsigned int u32;

__device__ __forceinline__ float bfu2f(u32 u16v) {
  return __uint_as_float(u16v << 16);
}
__device__ __forceinline__ u16 f2bfu(float f) {
  u32 u = __float_as_uint(f);
  return (u16)((u + 0x7fffu + ((u >> 16) & 1u)) >> 16);
}
__device__ __forceinline__ s16x8 ldpair(const u16* p) {
  s16x4 lo = *reinterpret_cast<const s16x4*>(p);
  s16x4 hi = *reinterpret_cast<const s16x4*>(p + 16);
  return __builtin_shufflevector(lo, hi, 0, 1, 2, 3, 4, 5, 6, 7);
}
__device__ __forceinline__ s16x8 ldb64pair(const u32* p) {
  s16x4 lo = *reinterpret_cast<const s16x4*>(p);
  s16x4 hi = *reinterpret_cast<const s16x4*>(p + 2);
  return __builtin_shufflevector(lo, hi, 0, 1, 2, 3, 4, 5, 6, 7);
}

// ---------------------------------------------------------------------------
// K0a: w_qkv fp32 -> bf16
// ---------------------------------------------------------------------------
__global__ __launch_bounds__(256) void k0_wcvt(const float* __restrict__ w,
                                               u16* __restrict__ wbf) {
  const int i = (blockIdx.x * 256 + threadIdx.x) * 4;
  f32x4 v = *reinterpret_cast<const f32x4*>(&w[i]);
  u16x4 o;
  o[0] = f2bfu(v[0]); o[1] = f2bfu(v[1]); o[2] = f2bfu(v[2]); o[3] = f2bfu(v[3]);
  *reinterpret_cast<u16x4*>(&wbf[i]) = o;
}

// ---------------------------------------------------------------------------
// K1 pipelined-persistent: 256 blocks x 4 panels, double-buffered panel LDS.
// Loads for panel j+1 issued to regs BEFORE compute(j); convert+LDS-write
// after. XCD k owns batch k. 512 thr.
// ---------------------------------------------------------------------------
__global__ __launch_bounds__(512, 1) void k1_qkv(
    const float* __restrict__ x, const u16* __restrict__ wbf,
    u16* __restrict__ qkv) {
  const int bid = blockIdx.x;
  const int base = (((bid & 7) << 5) + (bid >> 3)) << 2;   // 4-job chunk; XCD k -> batch k
  __shared__ u16 Xs[2][128 * LTK];
  const int t = threadIdx.x, lane = t & 63;
  const int wid = t >> 6, wo = wid >> 1, wn = wid & 1;
  const int l31 = lane & 31, g2 = lane >> 5;
  const int nq = t & 31, cr = t >> 5;
  const int kpb = cr >> 1, jh = cr & 1;
  const int prA = 2 * nq + jh, prB = 64 + 2 * nq + jh;

  f32x4 ld[12];
  // prologue: load + write panel(base) into buf0
  {
    const int b = base >> 7, p0 = base & 127;
    const float* xb = x + (size_t)b * CC * NN + (p0 << 7) + 4 * nq;
    #pragma unroll
    for (int i = 0; i < 12; ++i)
      ld[i] = *reinterpret_cast<const f32x4*>(xb + (size_t)(cr + 16 * i) * NN);
    u32* Xw = reinterpret_cast<u32*>(&Xs[0][0]);
    #pragma unroll
    for (int i = 0; i < 12; ++i) {
      f32x4 v = ld[i];
      u32 A  = (u32)f2bfu(v[0]) | ((u32)f2bfu(v[1]) << 16);
      u32 Bp = (u32)f2bfu(v[2]) | ((u32)f2bfu(v[3]) << 16);
      u32 oA = __shfl_xor(A, 32);
      u32 oB = __shfl_xor(Bp, 32);
      u32 va, vb;
      if (jh) {
        va = (oB & 0xffffu) | (Bp << 16);
        vb = (oB >> 16) | (Bp & 0xffff0000u);
      } else {
        va = (A & 0xffffu) | (oA << 16);
        vb = (A >> 16) | (oA & 0xffff0000u);
      }
      Xw[prA * LTK2 + kpb + 8 * i] = va;
      Xw[prB * LTK2 + kpb + 8 * i] = vb;
    }
  }
  __syncthreads();

  for (int j = 0; j < 4; ++j) {
    const int lin = base + j;
    const int b = lin >> 7, p0 = lin & 127;
    // issue next panel's loads (land during compute)
    if (j < 3) {
      const int lin2 = lin + 1;
      const int b2 = lin2 >> 7, p2 = lin2 & 127;
      const float* xb = x + (size_t)b2 * CC * NN + (p2 << 7) + 4 * nq;
      #pragma unroll
      for (int i = 0; i < 12; ++i)
        ld[i] = *reinterpret_cast<const f32x4*>(xb + (size_t)(cr + 16 * i) * NN);
    }
    // compute panel j
    const u32* Xsw = reinterpret_cast<const u32*>(&Xs[j & 1][0]);
    const u32* browE = &Xsw[(wn * 32 + l31) * LTK2 + 4 * g2];
    const u32* browO = &Xsw[(64 + wn * 32 + l31) * LTK2 + 4 * g2];
    u16* qbase = qkv + (size_t)b * C2 * NN + (p0 << 7);

    for (int ot = 0; ot < 3; ++ot) {
      const int o0 = ot * 128;
      const u16* wr = wbf + (size_t)(o0 + wo * 32 + l31) * CC + 8 * g2;
      s16x8 afA[6], afB[6];
      #pragma unroll
      for (int s = 0; s < 6; ++s) {
        afA[s] = *reinterpret_cast<const s16x8*>(wr + s * 32);
        afB[s] = *reinterpret_cast<const s16x8*>(wr + s * 32 + 16);
      }
      f32x16 accE, accO;
      #pragma unroll
      for (int e = 0; e < 16; ++e) { accE[e] = 0.f; accO[e] = 0.f; }
      #pragma unroll
      for (int s = 0; s < 6; ++s) {
        s16x8 bfE0 = ldb64pair(browE + 16 * s);
        s16x8 bfE1 = ldb64pair(browE + 16 * s + 8);
        s16x8 bfO0 = ldb64pair(browO + 16 * s);
        s16x8 bfO1 = ldb64pair(browO + 16 * s + 8);
        accE = __builtin_amdgcn_mfma_f32_32x32x16_bf16(afA[s], bfE0, accE, 0, 0, 0);
        accO = __builtin_amdgcn_mfma_f32_32x32x16_bf16(afA[s], bfO0, accO, 0, 0, 0);
        accE = __builtin_amdgcn_mfma_f32_32x32x16_bf16(afB[s], bfE1, accE, 0, 0, 0);
        accO = __builtin_amdgcn_mfma_f32_32x32x16_bf16(afB[s], bfO1, accO, 0, 0, 0);
      }
      #pragma unroll
      for (int r = 0; r < 16; ++r) {
        const int row = (r & 3) + 8 * (r >> 2) + 4 * g2;
        const u32 pk = (u32)f2bfu(accE[r]) | ((u32)f2bfu(accO[r]) << 16);
        *reinterpret_cast<u32*>(
            &qbase[(size_t)(o0 + wo * 32 + row) * NN + wn * 64 + 2 * l31]) = pk;
      }
    }
    // write next panel into other buffer
    if (j < 3) {
      __syncthreads();
      u32* Xw = reinterpret_cast<u32*>(&Xs[(j + 1) & 1][0]);
      #pragma unroll
      for (int i = 0; i < 12; ++i) {
        f32x4 v = ld[i];
        u32 A  = (u32)f2bfu(v[0]) | ((u32)f2bfu(v[1]) << 16);
        u32 Bp = (u32)f2bfu(v[2]) | ((u32)f2bfu(v[3]) << 16);
        u32 oA = __shfl_xor(A, 32);
        u32 oB = __shfl_xor(Bp, 32);
        u32 va, vb;
        if (jh) {
          va = (oB & 0xffffu) | (Bp << 16);
          vb = (oB >> 16) | (Bp & 0xffff0000u);
        } else {
          va = (A & 0xffffu) | (oA << 16);
          vb = (A >> 16) | (oA & 0xffff0000u);
        }
        Xw[prA * LTK2 + kpb + 8 * i] = va;
        Xw[prB * LTK2 + kpb + 8 * i] = vb;
      }
      __syncthreads();
    }
  }
}

// ---------------------------------------------------------------------------
// K2: 3x3 depthwise, all 384 channels, 8 px/thread (r9 version).
// ---------------------------------------------------------------------------
__global__ __launch_bounds__(256) void k2_dw(
    const u16* __restrict__ qkv, const float* __restrict__ wdw,
    u16* __restrict__ out) {
  const int gid = blockIdx.x;
  const int rb = gid & 7;
  const int plane = gid >> 3;
  const int ch = plane % C2;
  const int t = threadIdx.x;
  const int row = rb * 16 + (t >> 4);
  const int x0 = (t & 15) * 8;
  const u16* p = qkv + (size_t)plane * NN;
  const float* wv = wdw + ch * 9;
  float o[8];
  #pragma unroll
  for (int j = 0; j < 8; ++j) o[j] = 0.f;
  #pragma unroll
  for (int dy = 0; dy < 3; ++dy) {
    const int yy = row + dy - 1;
    if ((unsigned)yy < (unsigned)HH) {
      const u16* rp = p + yy * WW;
      u16x8 m = *reinterpret_cast<const u16x8*>(&rp[x0]);
      float px[10];
      px[0] = (x0 > 0) ? bfu2f(rp[x0 - 1]) : 0.f;
      px[9] = (x0 < 120) ? bfu2f(rp[x0 + 8]) : 0.f;
      #pragma unroll
      for (int j = 0; j < 8; ++j) px[j + 1] = bfu2f(m[j]);
      const float w0 = wv[dy * 3 + 0], w1 = wv[dy * 3 + 1], w2 = wv[dy * 3 + 2];
      #pragma unroll
      for (int j = 0; j < 8; ++j)
        o[j] += w0 * px[j] + w1 * px[j + 1] + w2 * px[j + 2];
    }
  }
  u16x8 ov;
  #pragma unroll
  for (int j = 0; j < 8; ++j) ov[j] = f2bfu(o[j]);
  *reinterpret_cast<u16x8*>(&out[(size_t)plane * NN + row * WW + x0]) = ov;
}

// ---------------------------------------------------------------------------
// K3: partial Gram via MFMA (r9 version).
// ---------------------------------------------------------------------------
__global__ __launch_bounds__(256) void k3_gram(
    const u16* __restrict__ qkvd, float* __restrict__ gpart) {
  const int bh = blockIdx.x, b = bh >> 2, h = bh & 3;
  const int chunk = blockIdx.y;
  const int t = threadIdx.x, lane = t & 63, wv = t >> 6;
  const int l15 = lane & 15, g = lane >> 4;
  __shared__ float red[4][2304];
  const u16* qb = qkvd + ((size_t)b * C2 + h * HC) * NN;

  f32x4 acc[3][3];
  #pragma unroll
  for (int i = 0; i < 3; ++i)
    #pragma unroll
    for (int j = 0; j < 3; ++j)
      #pragma unroll
      for (int e = 0; e < 4; ++e) acc[i][j][e] = 0.f;

  const int nbase = chunk * 1024 + wv * 256;
  #pragma unroll 2
  for (int st = 0; st < 8; ++st) {
    const int n = nbase + st * 32;
    s16x8 cf[3];
    #pragma unroll
    for (int i = 0; i < 3; ++i)
      cf[i] = ldpair(qb + (size_t)(i * 16 + l15) * NN + n + 4 * g);
    #pragma unroll
    for (int i = 0; i < 3; ++i)
      #pragma unroll
      for (int j = 0; j < 3; ++j)
        acc[i][j] = __builtin_amdgcn_mfma_f32_16x16x32_bf16(cf[i], cf[j], acc[i][j], 0, 0, 0);
  }
  #pragma unroll
  for (int i = 0; i < 3; ++i)
    #pragma unroll
    for (int j = 0; j < 3; ++j)
      #pragma unroll
      for (int r = 0; r < 4; ++r)
        red[wv][(i * 16 + 4 * g + r) * 48 + j * 16 + l15] = acc[i][j][r];
  __syncthreads();
  float* gp = gpart + ((size_t)bh * 16 + chunk) * 2304;
  for (int idx = t; idx < 2304; idx += 256)
    gp[idx] = red[0][idx] + red[1][idx] + red[2][idx] + red[3][idx];
}

// ---------------------------------------------------------------------------
// K4: reduce + normalize + softmax (r9 version, 16 chunks)
// ---------------------------------------------------------------------------
__global__ __launch_bounds__(256) void k4_soft(
    const float* __restrict__ gpart, const float* __restrict__ temp,
    float* __restrict__ attn) {
  const int bh = blockIdx.x;
  const int h = bh & 3;
  const int t = threadIdx.x;
  __shared__ float G[2304];
  __shared__ float rn[48];
  for (int idx = t; idx < 2304; idx += 256) {
    float s = 0.f;
    #pragma unroll
    for (int c = 0; c < 16; ++c) s += gpart[((size_t)bh * 16 + c) * 2304 + idx];
    G[idx] = s;
  }
  __syncthreads();
  if (t < 48) rn[t] = rsqrtf(G[t * 48 + t]);
  __syncthreads();
  if (t < 48) {
    const float tm = temp[h];
    float v[48];
    float mx = -1e30f;
    #pragma unroll
    for (int j = 0; j < 48; ++j) {
      v[j] = G[t * 48 + j] * rn[t] * rn[j] * tm;
      mx = fmaxf(mx, v[j]);
    }
    float s = 0.f;
    #pragma unroll
    for (int j = 0; j < 48; ++j) { v[j] = expf(v[j] - mx); s += v[j]; }
    const float inv = 1.f / s;
    #pragma unroll
    for (int j = 0; j < 48; ++j)
      attn[(size_t)bh * 2304 + t * 48 + j] = v[j] * inv;
  }
}

// ---------------------------------------------------------------------------
// K5: M = w_proj x blockdiag(attn) -> bf16 (unchanged)
// ---------------------------------------------------------------------------
__global__ __launch_bounds__(192) void k5_M(
    const float* __restrict__ wproj, const float* __restrict__ attn,
    u16* __restrict__ Mbf) {
  const int o = blockIdx.x;
  const int b = blockIdx.y;
  const int d = threadIdx.x;
  const int h = d / HC, dl = d % HC;
  const float* wrow = wproj + o * CC + h * HC;
  const float* at = attn + ((size_t)(b * NHEADS + h)) * 2304;
  float s = 0.f;
  #pragma unroll
  for (int c = 0; c < HC; ++c) s = fmaf(wrow[c], at[c * HC + dl], s);
  Mbf[((size_t)b * CC + o) * CC + d] = f2bfu(s);
}

// ---------------------------------------------------------------------------
// K6 pipelined-persistent: 256 blocks x 4 panels, double-buffered v LDS,
// loads issued before compute. 512 thr, 8 waves; pass0 o=0..127 (all waves),
// pass1 o=128..191 (waves wo<2). Nontemporal f32x2 out stores.
// ---------------------------------------------------------------------------
__global__ __launch_bounds__(512, 1) void k6_out(
    const u16* __restrict__ Mbf, const u16* __restrict__ qkvd,
    float* __restrict__ out) {
  const int bid = blockIdx.x;
  const int base = (((bid & 7) << 5) + (bid >> 3)) << 2;
  __shared__ u16 Vs[2][128 * LTK];
  const int t = threadIdx.x, lane = t & 63;
  const int wid = t >> 6, wo = wid >> 1, wn = wid & 1;
  const int l31 = lane & 31, g2 = lane >> 5;
  const int nq = t & 31, cr = t >> 5;
  const int kpb = cr >> 1, jh = cr & 1;
  const int prA = 2 * nq + jh, prB = 64 + 2 * nq + jh;

  u16x4 ld[12];
  {
    const int b = base >> 7, p0 = base & 127;
    const u16* vbp = qkvd + ((size_t)b * C2 + CC) * NN + (p0 << 7) + 4 * nq;
    #pragma unroll
    for (int i = 0; i < 12; ++i)
      ld[i] = *reinterpret_cast<const u16x4*>(vbp + (size_t)(cr + 16 * i) * NN);
    u32* Vw = reinterpret_cast<u32*>(&Vs[0][0]);
    #pragma unroll
    for (int i = 0; i < 12; ++i) {
      u16x4 m = ld[i];
      u32 A  = (u32)m[0] | ((u32)m[1] << 16);
      u32 Bp = (u32)m[2] | ((u32)m[3] << 16);
      u32 oA = __shfl_xor(A, 32);
      u32 oB = __shfl_xor(Bp, 32);
      u32 va, vb;
      if (jh) {
        va = (oB & 0xffffu) | (Bp << 16);
        vb = (oB >> 16) | (Bp & 0xffff0000u);
      } else {
        va = (A & 0xffffu) | (oA << 16);
        vb = (A >> 16) | (oA & 0xffff0000u);
      }
      Vw[prA * LTK2 + kpb + 8 * i] = va;
      Vw[prB * LTK2 + kpb + 8 * i] = vb;
    }
  }
  __syncthreads();

  for (int j = 0; j < 4; ++j) {
    const int lin = base + j;
    const int b = lin >> 7, p0 = lin & 127;
    if (j < 3) {
      const int lin2 = lin + 1;
      const int b2 = lin2 >> 7, p2 = lin2 & 127;
      const u16* vbp = qkvd + ((size_t)b2 * C2 + CC) * NN + (p2 << 7) + 4 * nq;
      #pragma unroll
      for (int i = 0; i < 12; ++i)
        ld[i] = *reinterpret_cast<const u16x4*>(vbp + (size_t)(cr + 16 * i) * NN);
    }
    const u32* Vsw = reinterpret_cast<const u32*>(&Vs[j & 1][0]);
    const u32* browE = &Vsw[(wn * 32 + l31) * LTK2 + 4 * g2];
    const u32* browO = &Vsw[(64 + wn * 32 + l31) * LTK2 + 4 * g2];
    const u16* Ab = Mbf + (size_t)b * CC * CC;
    float* obase = out + (size_t)b * CC * NN + (p0 << 7);

    #pragma unroll
    for (int ot = 0; ot < 2; ++ot) {
      const int o0 = ot * 128;
      const bool active = (ot == 0) || (wo < 2);
      if (active) {
        const u16* ar = Ab + (size_t)(o0 + wo * 32 + l31) * CC + 8 * g2;
        s16x8 afA[6], afB[6];
        #pragma unroll
        for (int s = 0; s < 6; ++s) {
          afA[s] = *reinterpret_cast<const s16x8*>(ar + s * 32);
          afB[s] = *reinterpret_cast<const s16x8*>(ar + s * 32 + 16);
        }
        f32x16 accE, accO;
        #pragma unroll
        for (int e = 0; e < 16; ++e) { accE[e] = 0.f; accO[e] = 0.f; }
        #pragma unroll
        for (int s = 0; s < 6; ++s) {
          s16x8 bfE0 = ldb64pair(browE + 16 * s);
          s16x8 bfE1 = ldb64pair(browE + 16 * s + 8);
          s16x8 bfO0 = ldb64pair(browO + 16 * s);
          s16x8 bfO1 = ldb64pair(browO + 16 * s + 8);
          accE = __builtin_amdgcn_mfma_f32_32x32x16_bf16(afA[s], bfE0, accE, 0, 0, 0);
          accO = __builtin_amdgcn_mfma_f32_32x32x16_bf16(afA[s], bfO0, accO, 0, 0, 0);
          accE = __builtin_amdgcn_mfma_f32_32x32x16_bf16(afB[s], bfE1, accE, 0, 0, 0);
          accO = __builtin_amdgcn_mfma_f32_32x32x16_bf16(afB[s], bfO1, accO, 0, 0, 0);
        }
        #pragma unroll
        for (int r = 0; r < 16; ++r) {
          const int row = (r & 3) + 8 * (r >> 2) + 4 * g2;
          f32x2 st;
          st[0] = accE[r];
          st[1] = accO[r];
          f32x2* op = reinterpret_cast<f32x2*>(
              &obase[(size_t)(o0 + wo * 32 + row) * NN + wn * 64 + 2 * l31]);
          __builtin_nontemporal_store(st, op);
        }
      }
    }
    if (j < 3) {
      __syncthreads();
      u32* Vw = reinterpret_cast<u32*>(&Vs[(j + 1) & 1][0]);
      #pragma unroll
      for (int i = 0; i < 12; ++i) {
        u16x4 m = ld[i];
        u32 A  = (u32)m[0] | ((u32)m[1] << 16);
        u32 Bp = (u32)m[2] | ((u32)m[3] << 16);
        u32 oA = __shfl_xor(A, 32);
        u32 oB = __shfl_xor(Bp, 32);
        u32 va, vb;
        if (jh) {
          va = (oB & 0xffffu) | (Bp << 16);
          vb = (oB >> 16) | (Bp & 0xffff0000u);
        } else {
          va = (A & 0xffffu) | (oA << 16);
          vb = (A >> 16) | (oA & 0xffff0000u);
        }
        Vw[prA * LTK2 + kpb + 8 * i] = va;
        Vw[prB * LTK2 + kpb + 8 * i] = vb;
      }
      __syncthreads();
    }
  }
}

// ---------------------------------------------------------------------------
extern "C" void kernel_launch(void* const* d_in, const int* in_sizes, int n_in,
                              void* d_out, int out_size, void* d_ws, size_t ws_size,
                              hipStream_t stream) {
  const float* x      = (const float*)d_in[0];
  const float* w_qkv  = (const float*)d_in[1];
  const float* w_dw   = (const float*)d_in[2];
  const float* w_proj = (const float*)d_in[3];
  const float* temp   = (const float*)d_in[4];
  float* out = (float*)d_out;

  const size_t OFF_QKV   = 0;               // bf16  8*384*16384 = 100,663,296
  const size_t OFF_QKVD  = 100663296ULL;    // bf16  same
  const size_t OFF_GPART = 201326592ULL;    // f32   32*16*2304  = 4,718,592
  const size_t OFF_ATTN  = 206045184ULL;    // f32   32*2304     = 294,912
  const size_t OFF_M     = 206340096ULL;    // bf16  8*192*192   = 589,824
  const size_t OFF_WBF   = 206929920ULL;    // bf16  384*192     = 147,456
  const size_t NEEDED    = 207077376ULL;
  if (ws_size < NEEDED) return;

  char* ws = (char*)d_ws;
  u16* qkv   = (u16*)(ws + OFF_QKV);
  u16* qkvd  = (u16*)(ws + OFF_QKVD);
  float* gpart = (float*)(ws + OFF_GPART);
  float* attn  = (float*)(ws + OFF_ATTN);
  u16* Mbf   = (u16*)(ws + OFF_M);
  u16* wbf   = (u16*)(ws + OFF_WBF);

  k0_wcvt<<<dim3(72), 256, 0, stream>>>(w_qkv, wbf);
  k1_qkv <<<dim3(256), 512, 0, stream>>>(x, wbf, qkv);
  k2_dw  <<<dim3(BB * C2 * 8), 256, 0, stream>>>(qkv, w_dw, qkvd);
  k3_gram<<<dim3(BB * NHEADS, 16), 256, 0, stream>>>(qkvd, gpart);
  k4_soft<<<dim3(BB * NHEADS), 256, 0, stream>>>(gpart, temp, attn);
  k5_M   <<<dim3(CC, BB), 192, 0, stream>>>(w_proj, attn, Mbf);
  k6_out <<<dim3(256), 512, 0, stream>>>(Mbf, qkvd, out);
}

// Round 15
// 214.245 us; speedup vs baseline: 1.1853x; 1.0567x over previous
//
#include <hip/hip_runtime.h>

#define BB 8
#define CC 192
#define C2 384
#define HH 128
#define WW 128
#define NN 16384
#define NHEADS 4
#define HC 48
#define LTK 196   // LDS row stride in u16 (392 B)
#define LTK2 98   // same in u32
// LDS physical row map: phys(n) = (n>>1) + 64*(n&1)

typedef float f32x2 __attribute__((ext_vector_type(2)));
typedef float f32x4 __attribute__((ext_vector_type(4)));
typedef float f32x16 __attribute__((ext_vector_type(16)));
typedef short s16x4 __attribute__((ext_vector_type(4)));
typedef short s16x8 __attribute__((ext_vector_type(8)));
typedef unsigned short u16;
typedef u16 u16x4 __attribute__((ext_vector_type(4)));
typedef u16 u16x8 __attribute__((ext_vector_type(8)));
typedef unsigned int u32;

__device__ __forceinline__ float bfu2f(u32 u16v) {
  return __uint_as_float(u16v << 16);
}
__device__ __forceinline__ u16 f2bfu(float f) {
  u32 u = __float_as_uint(f);
  return (u16)((u + 0x7fffu + ((u >> 16) & 1u)) >> 16);
}
__device__ __forceinline__ s16x8 ldpair(const u16* p) {
  s16x4 lo = *reinterpret_cast<const s16x4*>(p);
  s16x4 hi = *reinterpret_cast<const s16x4*>(p + 16);
  return __builtin_shufflevector(lo, hi, 0, 1, 2, 3, 4, 5, 6, 7);
}
__device__ __forceinline__ s16x8 ldb64pair(const u32* p) {
  s16x4 lo = *reinterpret_cast<const s16x4*>(p);
  s16x4 hi = *reinterpret_cast<const s16x4*>(p + 2);
  return __builtin_shufflevector(lo, hi, 0, 1, 2, 3, 4, 5, 6, 7);
}

// ---------------------------------------------------------------------------
// K0a: w_qkv fp32 -> bf16
// ---------------------------------------------------------------------------
__global__ __launch_bounds__(256) void k0_wcvt(const float* __restrict__ w,
                                               u16* __restrict__ wbf) {
  const int i = (blockIdx.x * 256 + threadIdx.x) * 4;
  f32x4 v = *reinterpret_cast<const f32x4*>(&w[i]);
  u16x4 o;
  o[0] = f2bfu(v[0]); o[1] = f2bfu(v[1]); o[2] = f2bfu(v[2]); o[3] = f2bfu(v[3]);
  *reinterpret_cast<u16x4*>(&wbf[i]) = o;
}

// ---------------------------------------------------------------------------
// K1 (r9 proven 97us): stage x-panel once, 3 o-tiles, E/O col frags,
// packed u32 stores, XCD-chunked n0. grid (128, 8), 512 thr.
// ---------------------------------------------------------------------------
__global__ __launch_bounds__(512, 4) void k1_qkv(
    const float* __restrict__ x, const u16* __restrict__ wbf,
    u16* __restrict__ qkv) {
  const int bx = blockIdx.x;
  const int n0 = (((bx & 7) << 4) + (bx >> 3)) << 7;   // XCD-chunked, bijective
  const int b  = blockIdx.y;
  __shared__ u16 Xs[128 * LTK];
  u32* Xsw = reinterpret_cast<u32*>(Xs);
  const int t = threadIdx.x, lane = t & 63;
  const int wid = t >> 6, wo = wid >> 1, wn = wid & 1;
  const int l31 = lane & 31, g2 = lane >> 5;

  {
    const int nq = t & 31, cr = t >> 5;
    const int kpb = cr >> 1;
    const int jh = cr & 1;
    const int prA = 2 * nq + jh;
    const int prB = 64 + 2 * nq + jh;
    const float* xb = x + (size_t)b * CC * NN + n0 + 4 * nq;
    #pragma unroll 6
    for (int i = 0; i < 12; ++i) {
      f32x4 v = *reinterpret_cast<const f32x4*>(xb + (size_t)(cr + 16 * i) * NN);
      u32 A  = (u32)f2bfu(v[0]) | ((u32)f2bfu(v[1]) << 16);
      u32 Bp = (u32)f2bfu(v[2]) | ((u32)f2bfu(v[3]) << 16);
      u32 oA = __shfl_xor(A, 32);
      u32 oB = __shfl_xor(Bp, 32);
      u32 va, vb;
      if (jh) {
        va = (oB & 0xffffu) | (Bp << 16);
        vb = (oB >> 16) | (Bp & 0xffff0000u);
      } else {
        va = (A & 0xffffu) | (oA << 16);
        vb = (A >> 16) | (oA & 0xffff0000u);
      }
      const int col = kpb + 8 * i;
      Xsw[prA * LTK2 + col] = va;
      Xsw[prB * LTK2 + col] = vb;
    }
  }
  __syncthreads();

  const int nb2 = wn * 32;
  const u32* browE = &Xsw[(nb2 + l31) * LTK2 + 4 * g2];
  const u32* browO = &Xsw[(64 + nb2 + l31) * LTK2 + 4 * g2];

  for (int ot = 0; ot < 3; ++ot) {
    const int o0 = ot * 128;
    const u16* wr = wbf + (size_t)(o0 + wo * 32 + l31) * CC + 8 * g2;

    s16x8 afA[6], afB[6];
    #pragma unroll
    for (int s = 0; s < 6; ++s) {
      afA[s] = *reinterpret_cast<const s16x8*>(wr + s * 32);
      afB[s] = *reinterpret_cast<const s16x8*>(wr + s * 32 + 16);
    }

    f32x16 accE, accO;
    #pragma unroll
    for (int e = 0; e < 16; ++e) { accE[e] = 0.f; accO[e] = 0.f; }

    #pragma unroll
    for (int s = 0; s < 6; ++s) {
      s16x8 bfE0 = ldb64pair(browE + 16 * s);
      s16x8 bfE1 = ldb64pair(browE + 16 * s + 8);
      s16x8 bfO0 = ldb64pair(browO + 16 * s);
      s16x8 bfO1 = ldb64pair(browO + 16 * s + 8);
      accE = __builtin_amdgcn_mfma_f32_32x32x16_bf16(afA[s], bfE0, accE, 0, 0, 0);
      accO = __builtin_amdgcn_mfma_f32_32x32x16_bf16(afA[s], bfO0, accO, 0, 0, 0);
      accE = __builtin_amdgcn_mfma_f32_32x32x16_bf16(afB[s], bfE1, accE, 0, 0, 0);
      accO = __builtin_amdgcn_mfma_f32_32x32x16_bf16(afB[s], bfO1, accO, 0, 0, 0);
    }
    #pragma unroll
    for (int r = 0; r < 16; ++r) {
      const int row = (r & 3) + 8 * (r >> 2) + 4 * g2;
      const u32 pk = (u32)f2bfu(accE[r]) | ((u32)f2bfu(accO[r]) << 16);
      *reinterpret_cast<u32*>(
          &qkv[((size_t)b * C2 + o0 + wo * 32 + row) * NN + n0 + wn * 64 + 2 * l31]) = pk;
    }
  }
}

// ---------------------------------------------------------------------------
// K2: 3x3 depthwise on the Q half only (v fused into k26). 8 px/thread.
// grid (B*192*8), 256 thr.
// ---------------------------------------------------------------------------
__global__ __launch_bounds__(256) void k2_dw(
    const u16* __restrict__ qkv, const float* __restrict__ wdw,
    u16* __restrict__ out) {
  const int gid = blockIdx.x;
  const int rb = gid & 7;
  const int p = gid >> 3;            // 0..1535
  const int b = p / 192, ch = p % 192;   // q channel
  const int plane = b * C2 + ch;
  const int t = threadIdx.x;
  const int row = rb * 16 + (t >> 4);
  const int x0 = (t & 15) * 8;
  const u16* pp = qkv + (size_t)plane * NN;
  const float* wv = wdw + ch * 9;
  float o[8];
  #pragma unroll
  for (int j = 0; j < 8; ++j) o[j] = 0.f;
  #pragma unroll
  for (int dy = 0; dy < 3; ++dy) {
    const int yy = row + dy - 1;
    if ((unsigned)yy < (unsigned)HH) {
      const u16* rp = pp + yy * WW;
      u16x8 m = *reinterpret_cast<const u16x8*>(&rp[x0]);
      float px[10];
      px[0] = (x0 > 0) ? bfu2f(rp[x0 - 1]) : 0.f;
      px[9] = (x0 < 120) ? bfu2f(rp[x0 + 8]) : 0.f;
      #pragma unroll
      for (int j = 0; j < 8; ++j) px[j + 1] = bfu2f(m[j]);
      const float w0 = wv[dy * 3 + 0], w1 = wv[dy * 3 + 1], w2 = wv[dy * 3 + 2];
      #pragma unroll
      for (int j = 0; j < 8; ++j)
        o[j] += w0 * px[j] + w1 * px[j + 1] + w2 * px[j + 2];
    }
  }
  u16x8 ov;
  #pragma unroll
  for (int j = 0; j < 8; ++j) ov[j] = f2bfu(o[j]);
  *reinterpret_cast<u16x8*>(&out[(size_t)plane * NN + row * WW + x0]) = ov;
}

// ---------------------------------------------------------------------------
// K3: partial Gram via MFMA (r9 version; reads q_dw half of qkvd).
// ---------------------------------------------------------------------------
__global__ __launch_bounds__(256) void k3_gram(
    const u16* __restrict__ qkvd, float* __restrict__ gpart) {
  const int bh = blockIdx.x, b = bh >> 2, h = bh & 3;
  const int chunk = blockIdx.y;
  const int t = threadIdx.x, lane = t & 63, wv = t >> 6;
  const int l15 = lane & 15, g = lane >> 4;
  __shared__ float red[4][2304];
  const u16* qb = qkvd + ((size_t)b * C2 + h * HC) * NN;

  f32x4 acc[3][3];
  #pragma unroll
  for (int i = 0; i < 3; ++i)
    #pragma unroll
    for (int j = 0; j < 3; ++j)
      #pragma unroll
      for (int e = 0; e < 4; ++e) acc[i][j][e] = 0.f;

  const int nbase = chunk * 1024 + wv * 256;
  #pragma unroll 2
  for (int st = 0; st < 8; ++st) {
    const int n = nbase + st * 32;
    s16x8 cf[3];
    #pragma unroll
    for (int i = 0; i < 3; ++i)
      cf[i] = ldpair(qb + (size_t)(i * 16 + l15) * NN + n + 4 * g);
    #pragma unroll
    for (int i = 0; i < 3; ++i)
      #pragma unroll
      for (int j = 0; j < 3; ++j)
        acc[i][j] = __builtin_amdgcn_mfma_f32_16x16x32_bf16(cf[i], cf[j], acc[i][j], 0, 0, 0);
  }
  #pragma unroll
  for (int i = 0; i < 3; ++i)
    #pragma unroll
    for (int j = 0; j < 3; ++j)
      #pragma unroll
      for (int r = 0; r < 4; ++r)
        red[wv][(i * 16 + 4 * g + r) * 48 + j * 16 + l15] = acc[i][j][r];
  __syncthreads();
  float* gp = gpart + ((size_t)bh * 16 + chunk) * 2304;
  for (int idx = t; idx < 2304; idx += 256)
    gp[idx] = red[0][idx] + red[1][idx] + red[2][idx] + red[3][idx];
}

// ---------------------------------------------------------------------------
// K4: reduce + normalize + softmax (r9 version, 16 chunks)
// ---------------------------------------------------------------------------
__global__ __launch_bounds__(256) void k4_soft(
    const float* __restrict__ gpart, const float* __restrict__ temp,
    float* __restrict__ attn) {
  const int bh = blockIdx.x;
  const int h = bh & 3;
  const int t = threadIdx.x;
  __shared__ float G[2304];
  __shared__ float rn[48];
  for (int idx = t; idx < 2304; idx += 256) {
    float s = 0.f;
    #pragma unroll
    for (int c = 0; c < 16; ++c) s += gpart[((size_t)bh * 16 + c) * 2304 + idx];
    G[idx] = s;
  }
  __syncthreads();
  if (t < 48) rn[t] = rsqrtf(G[t * 48 + t]);
  __syncthreads();
  if (t < 48) {
    const float tm = temp[h];
    float v[48];
    float mx = -1e30f;
    #pragma unroll
    for (int j = 0; j < 48; ++j) {
      v[j] = G[t * 48 + j] * rn[t] * rn[j] * tm;
      mx = fmaxf(mx, v[j]);
    }
    float s = 0.f;
    #pragma unroll
    for (int j = 0; j < 48; ++j) { v[j] = expf(v[j] - mx); s += v[j]; }
    const float inv = 1.f / s;
    #pragma unroll
    for (int j = 0; j < 48; ++j)
      attn[(size_t)bh * 2304 + t * 48 + j] = v[j] * inv;
  }
}

// ---------------------------------------------------------------------------
// K5: M = w_proj x blockdiag(attn) -> bf16 (unchanged)
// ---------------------------------------------------------------------------
__global__ __launch_bounds__(192) void k5_M(
    const float* __restrict__ wproj, const float* __restrict__ attn,
    u16* __restrict__ Mbf) {
  const int o = blockIdx.x;
  const int b = blockIdx.y;
  const int d = threadIdx.x;
  const int h = d / HC, dl = d % HC;
  const float* wrow = wproj + o * CC + h * HC;
  const float* at = attn + ((size_t)(b * NHEADS + h)) * 2304;
  float s = 0.f;
  #pragma unroll
  for (int c = 0; c < HC; ++c) s = fmaf(wrow[c], at[c * HC + dl], s);
  Mbf[((size_t)b * CC + o) * CC + d] = f2bfu(s);
}

// ---------------------------------------------------------------------------
// K26: FUSED v-half depthwise conv + (M x v_dw) output GEMM.
// Block = (row y, b): conv all 192 v-channels of image row y (k2-verbatim
// math, reads raw qkv v-half) directly into LDS Vs[phys(n)][d] (k6's exact
// fragment layout, phys(n)=(n>>1)+64*(n&1)); then k6-verbatim MFMA phase:
// out[o, y*128..] = sum_d M[o,d] * v_dw[d,n]. v_dw never hits HBM.
// grid (128 XCD-swizzled, 8), 256 thr, 50 KB LDS.
// ---------------------------------------------------------------------------
__global__ __launch_bounds__(256, 2) void k26_convout(
    const u16* __restrict__ qkv, const float* __restrict__ wdw,
    const u16* __restrict__ Mbf, float* __restrict__ out) {
  const int bx = blockIdx.x;
  const int y = ((bx & 7) << 4) + (bx >> 3);    // XCD-chunked, bijective 128
  const int b = blockIdx.y;
  __shared__ u16 Vs[128 * LTK];                 // [phys(n)][d], 50176 B
  const int t = threadIdx.x, lane = t & 63;
  const int wid = t >> 6, wo = wid >> 1, wn = wid & 1;
  const int l31 = lane & 31, g2 = lane >> 5;

  // ---- conv phase: thread -> (v-channel ch, 8-px group grp) x 12 iters ----
  #pragma unroll
  for (int it = 0; it < 12; ++it) {
    const int idx = t + 256 * it;      // 0..3071
    const int ch = idx >> 4;           // 0..191
    const int grp = idx & 15;
    const int x0 = grp * 8;
    const u16* pp = qkv + ((size_t)b * C2 + CC + ch) * NN;
    const float* wv = wdw + (CC + ch) * 9;
    float o[8];
    #pragma unroll
    for (int j = 0; j < 8; ++j) o[j] = 0.f;
    #pragma unroll
    for (int dy = 0; dy < 3; ++dy) {
      const int yy = y + dy - 1;
      if ((unsigned)yy < (unsigned)HH) {
        const u16* rp = pp + yy * WW;
        u16x8 m = *reinterpret_cast<const u16x8*>(&rp[x0]);
        float px[10];
        px[0] = (x0 > 0) ? bfu2f(rp[x0 - 1]) : 0.f;
        px[9] = (x0 < 120) ? bfu2f(rp[x0 + 8]) : 0.f;
        #pragma unroll
        for (int j = 0; j < 8; ++j) px[j + 1] = bfu2f(m[j]);
        const float w0 = wv[dy * 3 + 0], w1 = wv[dy * 3 + 1], w2 = wv[dy * 3 + 2];
        #pragma unroll
        for (int j = 0; j < 8; ++j)
          o[j] += w0 * px[j] + w1 * px[j + 1] + w2 * px[j + 2];
      }
    }
    #pragma unroll
    for (int j = 0; j < 8; ++j) {
      const int n = x0 + j;
      Vs[((n >> 1) + 64 * (n & 1)) * LTK + ch] = f2bfu(o[j]);
    }
  }
  __syncthreads();

  // ---- MFMA phase (k6 verbatim) ----
  const u32* Vsw = reinterpret_cast<const u32*>(Vs);
  const u32* browE = &Vsw[(wn * 32 + l31) * LTK2 + 4 * g2];
  const u32* browO = &Vsw[(64 + wn * 32 + l31) * LTK2 + 4 * g2];
  const u16* Ab = Mbf + (size_t)b * CC * CC;
  float* obase = out + (size_t)b * CC * NN + (y << 7);

  for (int ot = 0; ot < 3; ++ot) {
    const int o0 = ot * 64;
    const u16* ar = Ab + (size_t)(o0 + wo * 32 + l31) * CC + 8 * g2;

    s16x8 afA[6], afB[6];
    #pragma unroll
    for (int s = 0; s < 6; ++s) {
      afA[s] = *reinterpret_cast<const s16x8*>(ar + s * 32);
      afB[s] = *reinterpret_cast<const s16x8*>(ar + s * 32 + 16);
    }

    f32x16 accE, accO;
    #pragma unroll
    for (int e = 0; e < 16; ++e) { accE[e] = 0.f; accO[e] = 0.f; }

    #pragma unroll
    for (int s = 0; s < 6; ++s) {
      s16x8 bfE0 = ldb64pair(browE + 16 * s);
      s16x8 bfE1 = ldb64pair(browE + 16 * s + 8);
      s16x8 bfO0 = ldb64pair(browO + 16 * s);
      s16x8 bfO1 = ldb64pair(browO + 16 * s + 8);
      accE = __builtin_amdgcn_mfma_f32_32x32x16_bf16(afA[s], bfE0, accE, 0, 0, 0);
      accO = __builtin_amdgcn_mfma_f32_32x32x16_bf16(afA[s], bfO0, accO, 0, 0, 0);
      accE = __builtin_amdgcn_mfma_f32_32x32x16_bf16(afB[s], bfE1, accE, 0, 0, 0);
      accO = __builtin_amdgcn_mfma_f32_32x32x16_bf16(afB[s], bfO1, accO, 0, 0, 0);
    }
    #pragma unroll
    for (int r = 0; r < 16; ++r) {
      const int row = (r & 3) + 8 * (r >> 2) + 4 * g2;
      f32x2 st;
      st[0] = accE[r];
      st[1] = accO[r];
      f32x2* op = reinterpret_cast<f32x2*>(
          &obase[(size_t)(o0 + wo * 32 + row) * NN + wn * 64 + 2 * l31]);
      __builtin_nontemporal_store(st, op);
    }
  }
}

// ---------------------------------------------------------------------------
extern "C" void kernel_launch(void* const* d_in, const int* in_sizes, int n_in,
                              void* d_out, int out_size, void* d_ws, size_t ws_size,
                              hipStream_t stream) {
  const float* x      = (const float*)d_in[0];
  const float* w_qkv  = (const float*)d_in[1];
  const float* w_dw   = (const float*)d_in[2];
  const float* w_proj = (const float*)d_in[3];
  const float* temp   = (const float*)d_in[4];
  float* out = (float*)d_out;

  const size_t OFF_QKV   = 0;               // bf16  8*384*16384 = 100,663,296
  const size_t OFF_QKVD  = 100663296ULL;    // bf16  q_dw half used by k3
  const size_t OFF_GPART = 201326592ULL;    // f32   32*16*2304  = 4,718,592
  const size_t OFF_ATTN  = 206045184ULL;    // f32   32*2304     = 294,912
  const size_t OFF_M     = 206340096ULL;    // bf16  8*192*192   = 589,824
  const size_t OFF_WBF   = 206929920ULL;    // bf16  384*192     = 147,456
  const size_t NEEDED    = 207077376ULL;
  if (ws_size < NEEDED) return;

  char* ws = (char*)d_ws;
  u16* qkv   = (u16*)(ws + OFF_QKV);
  u16* qkvd  = (u16*)(ws + OFF_QKVD);
  float* gpart = (float*)(ws + OFF_GPART);
  float* attn  = (float*)(ws + OFF_ATTN);
  u16* Mbf   = (u16*)(ws + OFF_M);
  u16* wbf   = (u16*)(ws + OFF_WBF);

  k0_wcvt<<<dim3(72), 256, 0, stream>>>(w_qkv, wbf);
  k1_qkv <<<dim3(128, 8), 512, 0, stream>>>(x, wbf, qkv);
  k2_dw  <<<dim3(BB * 192 * 8), 256, 0, stream>>>(qkv, w_dw, qkvd);
  k3_gram<<<dim3(BB * NHEADS, 16), 256, 0, stream>>>(qkvd, gpart);
  k4_soft<<<dim3(BB * NHEADS), 256, 0, stream>>>(gpart, temp, attn);
  k5_M   <<<dim3(CC, BB), 192, 0, stream>>>(w_proj, attn, Mbf);
  k26_convout<<<dim3(128, 8), 256, 0, stream>>>(qkv, w_dw, Mbf, out);
}